// Round 3
// baseline (182.183 us; speedup 1.0000x reference)
//
#include <hip/hip_runtime.h>
#include <hip/hip_bf16.h>
#include <math.h>

// VariableSelectionNetwork — MI355X (gfx950), round 3
//
// Identity: scorer LayerNorm over a size-1 axis => its output == sc_ln_b,
// so softmax weights W[f] = softmax(sc_ln_b) are data-independent and the
// whole scorer GRN is dead code. Remaining: mix = x @ (W*proj_w)^T-ish + c,
// post-GRN (3x 256x256), gated skip, LayerNorm(256).
//
// Round-3 structure: prep kernels bake bf16 weights into ws (16B vector
// loads in the hot kernel), skip paths live in packed bf16 registers,
// single 8.4KB LDS transpose buffer, in-register LayerNorm via 16-lane
// shuffles. Occupancy 2 -> ~12 waves/CU.

typedef __bf16 bf16;
typedef __bf16 bf16x8 __attribute__((ext_vector_type(8)));
typedef __bf16 bf16x4 __attribute__((ext_vector_type(4)));
typedef float f32x4 __attribute__((ext_vector_type(4)));

#define NTOK 8192
#define D_   256
#define F_   32

// ws layout (bytes); total 425984 (416 KB)
#define OFF_C      512       // 256 f32
#define OFF_WPROJT 2048      // wprojT[d][f] bf16, 256*32
#define OFF_FC1    32768     // fc1_w bf16 [256][256]
#define OFF_FC2    163840    // fc2_w bf16 [256][256]
#define OFF_GATE   294912    // gate_w bf16 [256][256]

// ---- prep0: softmax(sc_ln_b) -> c[d], wprojT[d][f] = W[f]*proj_w[f][d] ----
__global__ __launch_bounds__(64) void vsn_prep0(
    const float* __restrict__ proj_w, const float* __restrict__ proj_b,
    const float* __restrict__ sc_ln_b,
    float* __restrict__ wsC, bf16* __restrict__ wsWT)
{
  __shared__ float sW[F_];
  const int lane = threadIdx.x;
  float logit = (lane < F_) ? sc_ln_b[lane] : -3.0e38f;
  float mx = logit;
  #pragma unroll
  for (int off = 32; off; off >>= 1) mx = fmaxf(mx, __shfl_xor(mx, off));
  float e = (lane < F_) ? __expf(logit - mx) : 0.0f;
  float se = e;
  #pragma unroll
  for (int off = 32; off; off >>= 1) se += __shfl_xor(se, off);
  if (lane < F_) sW[lane] = e / se;
  __syncthreads();
  #pragma unroll
  for (int i = 0; i < 4; i++) {
    int d = lane + 64 * i;
    float acc = 0.0f;
    #pragma unroll
    for (int f = 0; f < F_; f++) {
      float w = sW[f];
      acc += w * proj_b[f * D_ + d];
      wsWT[d * F_ + f] = (bf16)(w * proj_w[f * D_ + d]);
    }
    wsC[d] = acc;
  }
}

// ---- prep1: fp32 -> bf16 conversion of the three 256x256 weights ----
__global__ __launch_bounds__(256) void vsn_prep1(
    const float* __restrict__ w1, const float* __restrict__ w2,
    const float* __restrict__ w3,
    bf16* __restrict__ o1, bf16* __restrict__ o2, bf16* __restrict__ o3)
{
  int idx = blockIdx.x * 256 + threadIdx.x;   // 16384 float4s = 65536 floats
  {
    float4 a = ((const float4*)w1)[idx];
    bf16x4 b = {(bf16)a.x, (bf16)a.y, (bf16)a.z, (bf16)a.w};
    ((bf16x4*)o1)[idx] = b;
  }
  {
    float4 a = ((const float4*)w2)[idx];
    bf16x4 b = {(bf16)a.x, (bf16)a.y, (bf16)a.z, (bf16)a.w};
    ((bf16x4*)o2)[idx] = b;
  }
  {
    float4 a = ((const float4*)w3)[idx];
    bf16x4 b = {(bf16)a.x, (bf16)a.y, (bf16)a.z, (bf16)a.w};
    ((bf16x4*)o3)[idx] = b;
  }
}

// ---- main: 16 tokens per 1-wave block ----
__global__ __launch_bounds__(64, 3) void vsn_main(
    const float* __restrict__ x,
    const float* __restrict__ wsC,
    const bf16* __restrict__ WT,     // wprojT[d][f]
    const bf16* __restrict__ FC1, const float* __restrict__ fc1_b,
    const bf16* __restrict__ FC2, const float* __restrict__ fc2_b,
    const bf16* __restrict__ GATE, const float* __restrict__ gate_b,
    const float* __restrict__ ln_g, const float* __restrict__ ln_b,
    float* __restrict__ out)
{
  __shared__ bf16 sAct[16][264];   // one transpose buffer, reused 3x

  const int lane = threadIdx.x;
  const int tok0 = blockIdx.x * 16;
  const int lm = lane & 15;   // MFMA m (A-row) / n (B/C col)
  const int lq = lane >> 4;   // quad: A/B k-group, C row-group

  // ---- phase 1: mix = xb @ wprojT^T + c  (K = 32, one MFMA per j) ----
  const float* xp = x + (size_t)(tok0 + lm) * F_ + lq * 8;
  float4 x0 = *(const float4*)xp;
  float4 x1 = *(const float4*)(xp + 4);
  bf16x8 a0 = {(bf16)x0.x, (bf16)x0.y, (bf16)x0.z, (bf16)x0.w,
               (bf16)x1.x, (bf16)x1.y, (bf16)x1.z, (bf16)x1.w};
  bf16x4 mixh[16];                  // skip path, packed bf16 (C-layout ownership)
  #pragma unroll
  for (int j = 0; j < 16; j++) {
    int n = j * 16 + lm;
    float cv = wsC[n];
    f32x4 acc = {cv, cv, cv, cv};
    bf16x8 b = *(const bf16x8*)(WT + n * F_ + lq * 8);
    acc = __builtin_amdgcn_mfma_f32_16x16x32_bf16(a0, b, acc, 0, 0, 0);
    bf16x4 mh = {(bf16)acc[0], (bf16)acc[1], (bf16)acc[2], (bf16)acc[3]};
    mixh[j] = mh;
    #pragma unroll
    for (int r = 0; r < 4; r++) sAct[lq * 4 + r][n] = mh[r];
  }
  __syncthreads();

  // [16,256] @ W[256,256]^T ; A from sAct (LDS), B bf16x8 from global (L2)
  auto gemmB = [&](const bf16* __restrict__ W, f32x4* acc) {
    bf16x8 af[8];
    #pragma unroll
    for (int ks = 0; ks < 8; ks++)
      af[ks] = *(const bf16x8*)(&sAct[lm][ks * 32 + lq * 8]);
    #pragma unroll
    for (int j = 0; j < 16; j++) {
      f32x4 z = {0.f, 0.f, 0.f, 0.f};
      acc[j] = z;
      const bf16* wrow = W + (size_t)(j * 16 + lm) * 256 + lq * 8;
      #pragma unroll
      for (int ks = 0; ks < 8; ks++) {
        bf16x8 b = *(const bf16x8*)(wrow + ks * 32);
        acc[j] = __builtin_amdgcn_mfma_f32_16x16x32_bf16(af[ks], b, acc[j], 0, 0, 0);
      }
    }
  };

  // ---- phase 2: h1 = elu(mix @ fc1^T + b1) -> sAct ----
  {
    f32x4 acc[16];
    gemmB(FC1, acc);
    __syncthreads();
    #pragma unroll
    for (int j = 0; j < 16; j++) {
      int n = j * 16 + lm;
      float bias = fc1_b[n];
      #pragma unroll
      for (int r = 0; r < 4; r++) {
        float v = acc[j][r] + bias;
        v = (v > 0.0f) ? v : (__expf(v) - 1.0f);
        sAct[lq * 4 + r][n] = (bf16)v;
      }
    }
  }
  __syncthreads();

  // ---- phase 3: h2 = h1 @ fc2^T + b2 ; keep packed regs + sAct ----
  bf16x4 h2h[16];
  {
    f32x4 acc[16];
    gemmB(FC2, acc);
    __syncthreads();
    #pragma unroll
    for (int j = 0; j < 16; j++) {
      int n = j * 16 + lm;
      float bias = fc2_b[n];
      bf16x4 hh;
      #pragma unroll
      for (int r = 0; r < 4; r++) {
        hh[r] = (bf16)(acc[j][r] + bias);
        sAct[lq * 4 + r][n] = hh[r];
      }
      h2h[j] = hh;
    }
  }
  __syncthreads();

  // ---- phase 4: gate, gated skip, in-register LayerNorm, store ----
  f32x4 acc4[16];
  gemmB(GATE, acc4);
  #pragma unroll
  for (int j = 0; j < 16; j++) {
    int n = j * 16 + lm;
    float bias = gate_b[n];
    #pragma unroll
    for (int r = 0; r < 4; r++) {
      float s = acc4[j][r] + bias;
      float g = 1.0f / (1.0f + __expf(-s));
      acc4[j][r] = g * (float)h2h[j][r] + (1.0f - g) * (float)mixh[j][r];
    }
  }

  // LayerNorm over the 256 cols of each token row. Row m = lq*4+r lives
  // entirely in the 16 lanes sharing quad lq (16 j-values each) -> reduce
  // with shuffles confined to the 16-lane group (offsets 1,2,4,8).
  float mean[4], rstd[4];
  const float inv_d = 1.0f / 256.0f;
  #pragma unroll
  for (int r = 0; r < 4; r++) {
    float s = 0.0f;
    #pragma unroll
    for (int j = 0; j < 16; j++) s += acc4[j][r];
    #pragma unroll
    for (int off = 1; off < 16; off <<= 1) s += __shfl_xor(s, off);
    float m = s * inv_d;
    float q = 0.0f;
    #pragma unroll
    for (int j = 0; j < 16; j++) { float d = acc4[j][r] - m; q += d * d; }
    #pragma unroll
    for (int off = 1; off < 16; off <<= 1) q += __shfl_xor(q, off);
    mean[r] = m;
    rstd[r] = rsqrtf(q * inv_d + 1e-5f);
  }
  #pragma unroll
  for (int j = 0; j < 16; j++) {
    int n = j * 16 + lm;
    float lg = ln_g[n], lb = ln_b[n];
    #pragma unroll
    for (int r = 0; r < 4; r++) {
      float o = (acc4[j][r] - mean[r]) * rstd[r] * lg + lb;
      out[(size_t)(tok0 + lq * 4 + r) * D_ + n] = o;
    }
  }
}

extern "C" void kernel_launch(void* const* d_in, const int* in_sizes, int n_in,
                              void* d_out, int out_size, void* d_ws, size_t ws_size,
                              hipStream_t stream) {
  (void)in_sizes; (void)n_in; (void)ws_size; (void)out_size;
  const float* x      = (const float*)d_in[0];
  const float* proj_w = (const float*)d_in[1];
  const float* proj_b = (const float*)d_in[2];
  const float* sclnb  = (const float*)d_in[12];
  const float* fc1w   = (const float*)d_in[13];
  const float* fc1b   = (const float*)d_in[14];
  const float* fc2w   = (const float*)d_in[15];
  const float* fc2b   = (const float*)d_in[16];
  const float* gw     = (const float*)d_in[17];
  const float* gb     = (const float*)d_in[18];
  const float* lng    = (const float*)d_in[19];
  const float* lnb    = (const float*)d_in[20];

  char* ws = (char*)d_ws;
  float* wsC  = (float*)(ws + OFF_C);
  bf16*  wsWT = (bf16*)(ws + OFF_WPROJT);
  bf16*  bFC1 = (bf16*)(ws + OFF_FC1);
  bf16*  bFC2 = (bf16*)(ws + OFF_FC2);
  bf16*  bGATE= (bf16*)(ws + OFF_GATE);

  vsn_prep0<<<1, 64, 0, stream>>>(proj_w, proj_b, sclnb, wsC, wsWT);
  vsn_prep1<<<64, 256, 0, stream>>>(fc1w, fc2w, gw, bFC1, bFC2, bGATE);
  vsn_main<<<NTOK / 16, 64, 0, stream>>>(x, wsC, wsWT,
                                         bFC1, fc1b, bFC2, fc2b, bGATE, gb,
                                         lng, lnb, (float*)d_out);
}

// Round 4
// 126.869 us; speedup vs baseline: 1.4360x; 1.4360x over previous
//
#include <hip/hip_runtime.h>
#include <hip/hip_bf16.h>
#include <math.h>

// VariableSelectionNetwork — MI355X (gfx950), round 4
//
// Identity: scorer LayerNorm over a size-1 axis => output == sc_ln_b, so
// softmax weights W[f] = softmax(sc_ln_b) are constant and the scorer GRN is
// dead code. Remaining: mix = x @ WT^T + c ; post-GRN (3x 256x256) ; gated
// skip ; LayerNorm(256).
//
// Round 4: 4-wave blocks (j-split across waves) -> 8 waves/CU; explicit
// double-buffered B loads to break the load->mfma serial chain; single
// merged prep kernel.

typedef __bf16 bf16;
typedef __bf16 bf16x8 __attribute__((ext_vector_type(8)));
typedef __bf16 bf16x4 __attribute__((ext_vector_type(4)));
typedef float f32x4 __attribute__((ext_vector_type(4)));

#define NTOK 8192
#define D_   256
#define F_   32

// ws layout (bytes); total 416 KB
#define OFF_C      512
#define OFF_WPROJT 2048      // wprojT[d][f] bf16, 256*32
#define OFF_FC1    32768     // bf16 [256][256]
#define OFF_FC2    163840
#define OFF_GATE   294912

// ---- merged prep: blocks 0..63 convert 3 weights; block 64 does softmax/WT/c ----
__global__ __launch_bounds__(256) void vsn_prep(
    const float* __restrict__ proj_w, const float* __restrict__ proj_b,
    const float* __restrict__ sc_ln_b,
    const float* __restrict__ w1, const float* __restrict__ w2,
    const float* __restrict__ w3,
    float* __restrict__ wsC, bf16* __restrict__ wsWT,
    bf16* __restrict__ o1, bf16* __restrict__ o2, bf16* __restrict__ o3)
{
  const int blk = blockIdx.x;
  if (blk < 64) {
    int idx = blk * 256 + threadIdx.x;   // 16384 float4s per weight
    {
      float4 a = ((const float4*)w1)[idx];
      bf16x4 b = {(bf16)a.x, (bf16)a.y, (bf16)a.z, (bf16)a.w};
      ((bf16x4*)o1)[idx] = b;
    }
    {
      float4 a = ((const float4*)w2)[idx];
      bf16x4 b = {(bf16)a.x, (bf16)a.y, (bf16)a.z, (bf16)a.w};
      ((bf16x4*)o2)[idx] = b;
    }
    {
      float4 a = ((const float4*)w3)[idx];
      bf16x4 b = {(bf16)a.x, (bf16)a.y, (bf16)a.z, (bf16)a.w};
      ((bf16x4*)o3)[idx] = b;
    }
  } else {
    // every thread redundantly computes softmax(sc_ln_b) (32 broadcast loads)
    const int d = threadIdx.x;
    float wv[F_];
    float mx = -3.0e38f;
    #pragma unroll
    for (int f = 0; f < F_; f++) { wv[f] = sc_ln_b[f]; mx = fmaxf(mx, wv[f]); }
    float se = 0.0f;
    #pragma unroll
    for (int f = 0; f < F_; f++) { wv[f] = __expf(wv[f] - mx); se += wv[f]; }
    float inv = 1.0f / se;
    float acc = 0.0f;
    #pragma unroll
    for (int f = 0; f < F_; f++) {
      float wf = wv[f] * inv;
      acc += wf * proj_b[f * D_ + d];
      wsWT[d * F_ + f] = (bf16)(wf * proj_w[f * D_ + d]);
    }
    wsC[d] = acc;
  }
}

// ---- main: 16 tokens per 4-wave block; wave w owns output cols [64w,64w+64) ----
__global__ __launch_bounds__(256, 2) void vsn_main(
    const float* __restrict__ x,
    const float* __restrict__ wsC,
    const bf16* __restrict__ WT,
    const bf16* __restrict__ FC1, const float* __restrict__ fc1_b,
    const bf16* __restrict__ FC2, const float* __restrict__ fc2_b,
    const bf16* __restrict__ GATE, const float* __restrict__ gate_b,
    const float* __restrict__ ln_g, const float* __restrict__ ln_b,
    float* __restrict__ out)
{
  __shared__ bf16  sAct[16][264];   // bf16 activations (A operand), reused 3x
  __shared__ float sY[16][260];     // fp32 y2 for LayerNorm

  const int tid  = threadIdx.x;
  const int w    = tid >> 6;        // wave 0..3
  const int lane = tid & 63;
  const int lm   = lane & 15;       // MFMA m (A-row) / n (B/C col)
  const int lq   = lane >> 4;       // quad: k-group / C row-group
  const int j0   = w * 4;           // this wave's 4 n-tiles
  const int tok0 = blockIdx.x * 16;

  // ---- phase 1: mix = x @ WT^T + c  (K = 32, one MFMA per j) ----
  const float* xp = x + (size_t)(tok0 + lm) * F_ + lq * 8;
  float4 x0 = *(const float4*)xp;
  float4 x1 = *(const float4*)(xp + 4);
  bf16x8 a0 = {(bf16)x0.x, (bf16)x0.y, (bf16)x0.z, (bf16)x0.w,
               (bf16)x1.x, (bf16)x1.y, (bf16)x1.z, (bf16)x1.w};
  f32x4 mixf[4];                    // fp32 skip path, C-layout ownership
  #pragma unroll
  for (int jj = 0; jj < 4; jj++) {
    int n = (j0 + jj) * 16 + lm;
    float cv = wsC[n];
    f32x4 acc = {cv, cv, cv, cv};
    bf16x8 b = *(const bf16x8*)(WT + n * F_ + lq * 8);
    acc = __builtin_amdgcn_mfma_f32_16x16x32_bf16(a0, b, acc, 0, 0, 0);
    mixf[jj] = acc;
    #pragma unroll
    for (int r = 0; r < 4; r++) sAct[lq * 4 + r][n] = (bf16)acc[r];
  }
  __syncthreads();                  // mix ready in sAct

  bf16x8 af[8];
  auto loadA = [&]() {
    #pragma unroll
    for (int ks = 0; ks < 8; ks++)
      af[ks] = *(const bf16x8*)(&sAct[lm][ks * 32 + lq * 8]);
  };
  // [16,256] @ W^T restricted to this wave's 4 n-tiles, double-buffered B
  auto gemmB = [&](const bf16* __restrict__ W, f32x4* acc) {
    bf16x8 bb[8];
    const bf16* wp = W + (size_t)(j0 * 16 + lm) * 256 + lq * 8;
    #pragma unroll
    for (int ks = 0; ks < 8; ks++) bb[ks] = *(const bf16x8*)(wp + ks * 32);
    #pragma unroll
    for (int jj = 0; jj < 4; jj++) {
      bf16x8 bn[8];
      if (jj < 3) {
        const bf16* wn = W + (size_t)((j0 + jj + 1) * 16 + lm) * 256 + lq * 8;
        #pragma unroll
        for (int ks = 0; ks < 8; ks++) bn[ks] = *(const bf16x8*)(wn + ks * 32);
      }
      f32x4 a = {0.f, 0.f, 0.f, 0.f};
      acc[jj] = a;
      #pragma unroll
      for (int ks = 0; ks < 8; ks++)
        acc[jj] = __builtin_amdgcn_mfma_f32_16x16x32_bf16(af[ks], bb[ks], acc[jj], 0, 0, 0);
      if (jj < 3) {
        #pragma unroll
        for (int ks = 0; ks < 8; ks++) bb[ks] = bn[ks];
      }
    }
  };

  // ---- phase 2: h1 = elu(mix @ fc1^T + b1) ----
  loadA();
  __syncthreads();                  // all A reads done -> safe to overwrite
  {
    f32x4 acc[4];
    gemmB(FC1, acc);
    #pragma unroll
    for (int jj = 0; jj < 4; jj++) {
      int n = (j0 + jj) * 16 + lm;
      float bias = fc1_b[n];
      #pragma unroll
      for (int r = 0; r < 4; r++) {
        float v = acc[jj][r] + bias;
        v = (v > 0.0f) ? v : (__expf(v) - 1.0f);
        sAct[lq * 4 + r][n] = (bf16)v;
      }
    }
  }
  __syncthreads();                  // h1 ready

  // ---- phase 3: h2 = h1 @ fc2^T + b2 ----
  f32x4 h2f[4];
  loadA();
  __syncthreads();
  {
    f32x4 acc[4];
    gemmB(FC2, acc);
    #pragma unroll
    for (int jj = 0; jj < 4; jj++) {
      int n = (j0 + jj) * 16 + lm;
      float bias = fc2_b[n];
      #pragma unroll
      for (int r = 0; r < 4; r++) {
        float v = acc[jj][r] + bias;
        h2f[jj][r] = v;
        sAct[lq * 4 + r][n] = (bf16)v;
      }
    }
  }
  __syncthreads();                  // h2 ready

  // ---- phase 4: gate, gated skip -> sY (fp32) ----
  loadA();
  __syncthreads();
  {
    f32x4 acc[4];
    gemmB(GATE, acc);
    #pragma unroll
    for (int jj = 0; jj < 4; jj++) {
      int n = (j0 + jj) * 16 + lm;
      float bias = gate_b[n];
      #pragma unroll
      for (int r = 0; r < 4; r++) {
        float s = acc[jj][r] + bias;
        float g = 1.0f / (1.0f + __expf(-s));
        sY[lq * 4 + r][n] = g * h2f[jj][r] + (1.0f - g) * mixf[jj][r];
      }
    }
  }
  __syncthreads();                  // y2 ready

  // ---- phase 5: LayerNorm(256) — 16-lane group per token ----
  {
    const int t = w * 4 + lq;       // token 0..15
    float4 yv[4];
    #pragma unroll
    for (int i = 0; i < 4; i++)
      yv[i] = *(const float4*)(&sY[t][lm * 4 + i * 64]);
    const float inv_d = 1.0f / 256.0f;
    float s = 0.0f;
    #pragma unroll
    for (int i = 0; i < 4; i++) s += yv[i].x + yv[i].y + yv[i].z + yv[i].w;
    #pragma unroll
    for (int off = 1; off < 16; off <<= 1) s += __shfl_xor(s, off);
    float mean = s * inv_d;
    float q = 0.0f;
    #pragma unroll
    for (int i = 0; i < 4; i++) {
      float d0 = yv[i].x - mean, d1 = yv[i].y - mean,
            d2 = yv[i].z - mean, d3 = yv[i].w - mean;
      q += d0 * d0 + d1 * d1 + d2 * d2 + d3 * d3;
    }
    #pragma unroll
    for (int off = 1; off < 16; off <<= 1) q += __shfl_xor(q, off);
    float rstd = rsqrtf(q * inv_d + 1e-5f);
    #pragma unroll
    for (int i = 0; i < 4; i++) {
      int n = lm * 4 + i * 64;
      float4 gv = *(const float4*)(ln_g + n);
      float4 bv = *(const float4*)(ln_b + n);
      float4 o;
      o.x = (yv[i].x - mean) * rstd * gv.x + bv.x;
      o.y = (yv[i].y - mean) * rstd * gv.y + bv.y;
      o.z = (yv[i].z - mean) * rstd * gv.z + bv.z;
      o.w = (yv[i].w - mean) * rstd * gv.w + bv.w;
      *(float4*)(out + (size_t)(tok0 + t) * D_ + n) = o;
    }
  }
}

extern "C" void kernel_launch(void* const* d_in, const int* in_sizes, int n_in,
                              void* d_out, int out_size, void* d_ws, size_t ws_size,
                              hipStream_t stream) {
  (void)in_sizes; (void)n_in; (void)ws_size; (void)out_size;
  const float* x      = (const float*)d_in[0];
  const float* proj_w = (const float*)d_in[1];
  const float* proj_b = (const float*)d_in[2];
  const float* sclnb  = (const float*)d_in[12];
  const float* fc1w   = (const float*)d_in[13];
  const float* fc1b   = (const float*)d_in[14];
  const float* fc2w   = (const float*)d_in[15];
  const float* fc2b   = (const float*)d_in[16];
  const float* gw     = (const float*)d_in[17];
  const float* gb     = (const float*)d_in[18];
  const float* lng    = (const float*)d_in[19];
  const float* lnb    = (const float*)d_in[20];

  char* ws = (char*)d_ws;
  float* wsC   = (float*)(ws + OFF_C);
  bf16*  wsWT  = (bf16*)(ws + OFF_WPROJT);
  bf16*  bFC1  = (bf16*)(ws + OFF_FC1);
  bf16*  bFC2  = (bf16*)(ws + OFF_FC2);
  bf16*  bGATE = (bf16*)(ws + OFF_GATE);

  vsn_prep<<<65, 256, 0, stream>>>(proj_w, proj_b, sclnb, fc1w, fc2w, gw,
                                   wsC, wsWT, bFC1, bFC2, bGATE);
  vsn_main<<<NTOK / 16, 256, 0, stream>>>(x, wsC, wsWT,
                                          bFC1, fc1b, bFC2, fc2b, bGATE, gb,
                                          lng, lnb, (float*)d_out);
}

// Round 5
// 113.393 us; speedup vs baseline: 1.6067x; 1.1188x over previous
//
#include <hip/hip_runtime.h>
#include <hip/hip_bf16.h>
#include <math.h>

// VariableSelectionNetwork — MI355X (gfx950), round 5
//
// Identity: scorer LayerNorm over a size-1 axis => output == sc_ln_b, so
// softmax weights W[f] = softmax(sc_ln_b) are constant and the scorer GRN is
// dead code. Remaining: mix = x @ WT^T + c ; post-GRN (3x 256x256) ; gated
// skip ; LayerNorm(256).
//
// Round 5: weights pre-swizzled into MFMA-fragment order (every B load is a
// contiguous 1KB/wave segment — round 4's were 16-way scattered); M=32 per
// block (2 A-tiles share each B register => half the weight traffic, 2x MFMA
// per load-wait); ping-pong activation LDS (1 barrier/phase).

typedef __bf16 bf16;
typedef __bf16 bf16x8 __attribute__((ext_vector_type(8)));
typedef __bf16 bf16x4 __attribute__((ext_vector_type(4)));
typedef float f32x4 __attribute__((ext_vector_type(4)));

#define NTOK 8192
#define D_   256
#define F_   32

// ws layout (bytes)
#define OFF_C      512       // 256 f32
#define OFF_WPROJT 2048      // WT[n][f] bf16 (already fragment-coalesced), 16 KB
#define OFF_FC1    32768     // swizzled bf16, 128 KB each
#define OFF_FC2    163840
#define OFF_GATE   294912

// Swizzled layout: SW[elem] with elem = j*4096 + ks*512 + lm*32 + lq*8 + e
//   == W[row = j*16+lm][col = ks*32 + lq*8 + e],  j<16, ks<8, lm<16, lq<4, e<8.
// A wave's (j,ks) fragment load covers elems [j*4096+ks*512, +512) = 1KB contig.

// ---- prep: blocks 0..23 swizzle-convert 3 weights; block 24 softmax/WT/c ----
__global__ __launch_bounds__(256) void vsn_prep(
    const float* __restrict__ proj_w, const float* __restrict__ proj_b,
    const float* __restrict__ sc_ln_b,
    const float* __restrict__ w1, const float* __restrict__ w2,
    const float* __restrict__ w3,
    float* __restrict__ wsC, bf16* __restrict__ wsWT,
    bf16* __restrict__ o1, bf16* __restrict__ o2, bf16* __restrict__ o3)
{
  const int blk = blockIdx.x;
  if (blk < 24) {
    int g = blk * 256 + threadIdx.x;          // 0..6143
    int m = g >> 11;                          // matrix 0..2
    int c = g & 2047;                         // chunk: row = c>>3, ks = c&7
    const float* src = (m == 0) ? w1 : (m == 1) ? w2 : w3;
    bf16* dst = (m == 0) ? o1 : (m == 1) ? o2 : o3;
    int row = c >> 3, ks = c & 7;
    int j = row >> 4, lm = row & 15;
    const float* sp = src + row * 256 + ks * 32;   // 32 contig floats
    bf16* dp = dst + j * 4096 + ks * 512 + lm * 32;
    #pragma unroll
    for (int q = 0; q < 4; q++) {
      float4 a = ((const float4*)sp)[2 * q];
      float4 b = ((const float4*)sp)[2 * q + 1];
      bf16x8 v = {(bf16)a.x, (bf16)a.y, (bf16)a.z, (bf16)a.w,
                  (bf16)b.x, (bf16)b.y, (bf16)b.z, (bf16)b.w};
      *(bf16x8*)(dp + q * 8) = v;
    }
  } else {
    // thread d: softmax(sc_ln_b) redundantly, then WT row + c[d]
    const int d = threadIdx.x;
    float wv[F_];
    float mx = -3.0e38f;
    #pragma unroll
    for (int f = 0; f < F_; f++) { wv[f] = sc_ln_b[f]; mx = fmaxf(mx, wv[f]); }
    float se = 0.0f;
    #pragma unroll
    for (int f = 0; f < F_; f++) { wv[f] = __expf(wv[f] - mx); se += wv[f]; }
    float inv = 1.0f / se;
    float acc = 0.0f;
    #pragma unroll
    for (int f = 0; f < F_; f++) {
      float wf = wv[f] * inv;
      acc += wf * proj_b[f * D_ + d];
      wsWT[d * F_ + f] = (bf16)(wf * proj_w[f * D_ + d]);
    }
    wsC[d] = acc;
  }
}

// ---- main: 32 tokens / 4-wave block; wave w owns cols [64w,64w+64), 2 A-tiles ----
__global__ __launch_bounds__(256, 1) void vsn_main(
    const float* __restrict__ x,
    const float* __restrict__ wsC,
    const bf16* __restrict__ WT,
    const bf16* __restrict__ FC1, const float* __restrict__ fc1_b,
    const bf16* __restrict__ FC2, const float* __restrict__ fc2_b,
    const bf16* __restrict__ GATE, const float* __restrict__ gate_b,
    const float* __restrict__ ln_g, const float* __restrict__ ln_b,
    float* __restrict__ out)
{
  __shared__ bf16  sAct[2][32][264];   // ping-pong bf16 activations (A operand)
  __shared__ float sY[32][260];        // fp32 y2 for LayerNorm

  const int tid  = threadIdx.x;
  const int w    = tid >> 6;
  const int lane = tid & 63;
  const int lm   = lane & 15;
  const int lq   = lane >> 4;
  const int j0   = w * 4;
  const int tok0 = blockIdx.x * 32;

  // ---- phase 1: mix = x @ WT^T + c (K=32); 2 tiles share each B ----
  bf16x4 mixh[2][4];
  {
    bf16x8 a[2];
    #pragma unroll
    for (int t = 0; t < 2; t++) {
      const float* xp = x + (size_t)(tok0 + t * 16 + lm) * F_ + lq * 8;
      float4 x0 = *(const float4*)xp;
      float4 x1 = *(const float4*)(xp + 4);
      bf16x8 av = {(bf16)x0.x, (bf16)x0.y, (bf16)x0.z, (bf16)x0.w,
                   (bf16)x1.x, (bf16)x1.y, (bf16)x1.z, (bf16)x1.w};
      a[t] = av;
    }
    #pragma unroll
    for (int jj = 0; jj < 4; jj++) {
      int n = (j0 + jj) * 16 + lm;
      bf16x8 b = *(const bf16x8*)(WT + n * F_ + lq * 8);   // 1KB/wave contig
      float cv = wsC[n];
      #pragma unroll
      for (int t = 0; t < 2; t++) {
        f32x4 acc = {cv, cv, cv, cv};
        acc = __builtin_amdgcn_mfma_f32_16x16x32_bf16(a[t], b, acc, 0, 0, 0);
        bf16x4 mh = {(bf16)acc[0], (bf16)acc[1], (bf16)acc[2], (bf16)acc[3]};
        mixh[t][jj] = mh;
        #pragma unroll
        for (int r = 0; r < 4; r++) sAct[0][t * 16 + lq * 4 + r][n] = mh[r];
      }
    }
  }
  __syncthreads();

  // generic phase: read A-tiles from sAct[src], gemm vs swizzled W, epilogue
  auto gemmPhase = [&](int src, const bf16* __restrict__ W, auto&& epi) {
    bf16x8 af[2][8];
    #pragma unroll
    for (int t = 0; t < 2; t++)
      #pragma unroll
      for (int ks = 0; ks < 8; ks++)
        af[t][ks] = *(const bf16x8*)(&sAct[src][t * 16 + lm][ks * 32 + lq * 8]);
    const bf16* base = W + j0 * 4096 + lm * 32 + lq * 8;
    bf16x8 bb[8];
    #pragma unroll
    for (int ks = 0; ks < 8; ks++)
      bb[ks] = *(const bf16x8*)(base + ks * 512);          // 1KB/wave contig
    #pragma unroll
    for (int jj = 0; jj < 4; jj++) {
      bf16x8 bn[8];
      if (jj < 3) {
        const bf16* nb = base + (jj + 1) * 4096;
        #pragma unroll
        for (int ks = 0; ks < 8; ks++)
          bn[ks] = *(const bf16x8*)(nb + ks * 512);
      }
      f32x4 acc0 = {0.f, 0.f, 0.f, 0.f}, acc1 = {0.f, 0.f, 0.f, 0.f};
      #pragma unroll
      for (int ks = 0; ks < 8; ks++) {
        acc0 = __builtin_amdgcn_mfma_f32_16x16x32_bf16(af[0][ks], bb[ks], acc0, 0, 0, 0);
        acc1 = __builtin_amdgcn_mfma_f32_16x16x32_bf16(af[1][ks], bb[ks], acc1, 0, 0, 0);
      }
      epi(jj, acc0, acc1);
      if (jj < 3) {
        #pragma unroll
        for (int ks = 0; ks < 8; ks++) bb[ks] = bn[ks];
      }
    }
  };

  // ---- phase 2: h1 = elu(mix @ fc1^T + b1) -> sAct[1] ----
  gemmPhase(0, FC1, [&](int jj, f32x4& a0, f32x4& a1) {
    int n = (j0 + jj) * 16 + lm;
    float bias = fc1_b[n];
    #pragma unroll
    for (int r = 0; r < 4; r++) {
      float v0 = a0[r] + bias;
      v0 = (v0 > 0.0f) ? v0 : (__expf(v0) - 1.0f);
      sAct[1][lq * 4 + r][n] = (bf16)v0;
      float v1 = a1[r] + bias;
      v1 = (v1 > 0.0f) ? v1 : (__expf(v1) - 1.0f);
      sAct[1][16 + lq * 4 + r][n] = (bf16)v1;
    }
  });
  __syncthreads();

  // ---- phase 3: h2 = h1 @ fc2^T + b2 -> sAct[0], keep packed regs ----
  bf16x4 h2h[2][4];
  gemmPhase(1, FC2, [&](int jj, f32x4& a0, f32x4& a1) {
    int n = (j0 + jj) * 16 + lm;
    float bias = fc2_b[n];
    bf16x4 h0, h1v;
    #pragma unroll
    for (int r = 0; r < 4; r++) {
      h0[r]  = (bf16)(a0[r] + bias);
      h1v[r] = (bf16)(a1[r] + bias);
      sAct[0][lq * 4 + r][n] = h0[r];
      sAct[0][16 + lq * 4 + r][n] = h1v[r];
    }
    h2h[0][jj] = h0;
    h2h[1][jj] = h1v;
  });
  __syncthreads();

  // ---- phase 4: gate, gated skip -> sY ----
  gemmPhase(0, GATE, [&](int jj, f32x4& a0, f32x4& a1) {
    int n = (j0 + jj) * 16 + lm;
    float bias = gate_b[n];
    #pragma unroll
    for (int r = 0; r < 4; r++) {
      float s0 = a0[r] + bias;
      float g0 = 1.0f / (1.0f + __expf(-s0));
      sY[lq * 4 + r][n] = g0 * (float)h2h[0][jj][r] + (1.0f - g0) * (float)mixh[0][jj][r];
      float s1 = a1[r] + bias;
      float g1 = 1.0f / (1.0f + __expf(-s1));
      sY[16 + lq * 4 + r][n] = g1 * (float)h2h[1][jj][r] + (1.0f - g1) * (float)mixh[1][jj][r];
    }
  });
  __syncthreads();

  // ---- phase 5: LayerNorm(256); 16-lane group handles 2 tokens ----
  const float inv_d = 1.0f / 256.0f;
  #pragma unroll
  for (int rep = 0; rep < 2; rep++) {
    const int t = (w * 4 + lq) * 2 + rep;
    float4 yv[4];
    #pragma unroll
    for (int i = 0; i < 4; i++)
      yv[i] = *(const float4*)(&sY[t][lm * 4 + i * 64]);
    float s = 0.0f;
    #pragma unroll
    for (int i = 0; i < 4; i++) s += yv[i].x + yv[i].y + yv[i].z + yv[i].w;
    #pragma unroll
    for (int off = 1; off < 16; off <<= 1) s += __shfl_xor(s, off);
    float mean = s * inv_d;
    float q = 0.0f;
    #pragma unroll
    for (int i = 0; i < 4; i++) {
      float d0 = yv[i].x - mean, d1 = yv[i].y - mean,
            d2 = yv[i].z - mean, d3 = yv[i].w - mean;
      q += d0 * d0 + d1 * d1 + d2 * d2 + d3 * d3;
    }
    #pragma unroll
    for (int off = 1; off < 16; off <<= 1) q += __shfl_xor(q, off);
    float rstd = rsqrtf(q * inv_d + 1e-5f);
    #pragma unroll
    for (int i = 0; i < 4; i++) {
      int n = lm * 4 + i * 64;
      float4 gv = *(const float4*)(ln_g + n);
      float4 bv = *(const float4*)(ln_b + n);
      float4 o;
      o.x = (yv[i].x - mean) * rstd * gv.x + bv.x;
      o.y = (yv[i].y - mean) * rstd * gv.y + bv.y;
      o.z = (yv[i].z - mean) * rstd * gv.z + bv.z;
      o.w = (yv[i].w - mean) * rstd * gv.w + bv.w;
      *(float4*)(out + (size_t)(tok0 + t) * D_ + n) = o;
    }
  }
}

extern "C" void kernel_launch(void* const* d_in, const int* in_sizes, int n_in,
                              void* d_out, int out_size, void* d_ws, size_t ws_size,
                              hipStream_t stream) {
  (void)in_sizes; (void)n_in; (void)ws_size; (void)out_size;
  const float* x      = (const float*)d_in[0];
  const float* proj_w = (const float*)d_in[1];
  const float* proj_b = (const float*)d_in[2];
  const float* sclnb  = (const float*)d_in[12];
  const float* fc1w   = (const float*)d_in[13];
  const float* fc1b   = (const float*)d_in[14];
  const float* fc2w   = (const float*)d_in[15];
  const float* fc2b   = (const float*)d_in[16];
  const float* gw     = (const float*)d_in[17];
  const float* gb     = (const float*)d_in[18];
  const float* lng    = (const float*)d_in[19];
  const float* lnb    = (const float*)d_in[20];

  char* ws = (char*)d_ws;
  float* wsC   = (float*)(ws + OFF_C);
  bf16*  wsWT  = (bf16*)(ws + OFF_WPROJT);
  bf16*  bFC1  = (bf16*)(ws + OFF_FC1);
  bf16*  bFC2  = (bf16*)(ws + OFF_FC2);
  bf16*  bGATE = (bf16*)(ws + OFF_GATE);

  vsn_prep<<<25, 256, 0, stream>>>(proj_w, proj_b, sclnb, fc1w, fc2w, gw,
                                   wsC, wsWT, bFC1, bFC2, bGATE);
  vsn_main<<<NTOK / 32, 256, 0, stream>>>(x, wsC, wsWT,
                                          bFC1, fc1b, bFC2, fc2b, bGATE, gb,
                                          lng, lnb, (float*)d_out);
}